// Round 11
// baseline (1266.797 us; speedup 1.0000x reference)
//
#include <hip/hip_runtime.h>
#include <hip/hip_bf16.h>
#include <math.h>

typedef __attribute__((ext_vector_type(4))) float f32x4;
typedef __attribute__((ext_vector_type(8))) short s16x8;

#define BB 2
#define SS 1024
#define MEM 1024
#define DD 1024
#define LL 4
#define VV 32000
#define TT 2048
#define NH 16
#define DH 64

__device__ __forceinline__ short f2bf(float f) {
    unsigned u = __float_as_uint(f);
    u += 0x7fffu + ((u >> 16) & 1u);   // round-to-nearest-even
    return (short)(u >> 16);
}

__device__ __forceinline__ float gelu_f(float x) {
    return 0.5f * x * (1.0f + erff(x * 0.70710678118654752f));
}

__device__ __forceinline__ void gll16(const short* g, short* l) {
    __builtin_amdgcn_global_load_lds(
        (__attribute__((address_space(1))) void*)(short*)g,
        (__attribute__((address_space(3))) void*)l, 16, 0, 0);
}

// ---------------- GEMM small-shape: BK=128, 2-barrier (R5 structure) -------
template<int WM, int WN>
__global__ __launch_bounds__(256) void gemm_k128(
    const short* __restrict__ A, const short* __restrict__ Bt,
    const float* __restrict__ bias, const float* __restrict__ bias2,
    int nsplit, void* __restrict__ Cv, int N, int K, int nby, int act, int obf)
{
    constexpr int BM = WM * 32, BN = WN * 32;
    constexpr int NA = BM / 16, NB = BN / 16;
    __shared__ short a_s[BM * 128];
    __shared__ short b_s[BN * 128];
    const int tid  = threadIdx.x;
    const int lane = tid & 63;
    const int wave = tid >> 6;
    const int wr = wave >> 1, wc = wave & 1;
    const int fr = lane & 15, fg = lane >> 4;

    const int nwg = gridDim.x;
    const int bid = blockIdx.x;
    const int swz = ((nwg & 7) == 0) ? ((bid & 7) * (nwg >> 3) + (bid >> 3)) : bid;
    const size_t m0 = (size_t)(swz % nby) * BM;
    const size_t n0 = (size_t)(swz / nby) * BN;

    const short* gA[NA]; short* lA[NA];
    const short* gB[NB]; short* lB[NB];
    #pragma unroll
    for (int i = 0; i < NA; ++i) {
        gA[i] = A + (m0 + i * 16 + (tid & 15)) * (size_t)K + (tid >> 4) * 8;
        lA[i] = &a_s[(i * 256 + tid) * 8];
    }
    #pragma unroll
    for (int i = 0; i < NB; ++i) {
        gB[i] = Bt + (n0 + i * 16 + (tid & 15)) * (size_t)K + (tid >> 4) * 8;
        lB[i] = &b_s[(i * 256 + tid) * 8];
    }

    f32x4 acc[WM][WN] = {};

    #pragma unroll
    for (int i = 0; i < NA; ++i) gll16(gA[i], lA[i]);
    #pragma unroll
    for (int i = 0; i < NB; ++i) gll16(gB[i], lB[i]);

    const int nt = K >> 7;
    for (int t = 0; t < nt; ++t) {
        __syncthreads();
        s16x8 af[WM][4], bf[WN][4];
        #pragma unroll
        for (int mi = 0; mi < WM; ++mi)
            #pragma unroll
            for (int h = 0; h < 4; ++h)
                af[mi][h] = *(const s16x8*)&a_s[((wr*WM + mi)*256 + (4*h + fg)*16 + fr) * 8];
        #pragma unroll
        for (int ni = 0; ni < WN; ++ni)
            #pragma unroll
            for (int h = 0; h < 4; ++h)
                bf[ni][h] = *(const s16x8*)&b_s[((wc*WN + ni)*256 + (4*h + fg)*16 + fr) * 8];
        if (t + 1 < nt) {
            __syncthreads();
            const int koff = (t + 1) << 7;
            #pragma unroll
            for (int i = 0; i < NA; ++i) gll16(gA[i] + koff, lA[i]);
            #pragma unroll
            for (int i = 0; i < NB; ++i) gll16(gB[i] + koff, lB[i]);
        }
        #pragma unroll
        for (int mi = 0; mi < WM; ++mi)
            #pragma unroll
            for (int ni = 0; ni < WN; ++ni)
                #pragma unroll
                for (int h = 0; h < 4; ++h)
                    acc[mi][ni] = __builtin_amdgcn_mfma_f32_16x16x32_bf16(
                        af[mi][h], bf[ni][h], acc[mi][ni], 0, 0, 0);
    }

    float* Cf = (float*)Cv;
    short* Cb = (short*)Cv;
    #pragma unroll
    for (int mi = 0; mi < WM; ++mi) {
        #pragma unroll
        for (int ni = 0; ni < WN; ++ni) {
            const size_t r0 = m0 + wr*WM*16 + mi*16 + fg*4;
            const size_t c  = n0 + wc*WN*16 + ni*16 + fr;
            const float bb = (c < (size_t)nsplit) ? bias[c] : bias2[c - nsplit];
            #pragma unroll
            for (int rg = 0; rg < 4; ++rg) {
                float vv = acc[mi][ni][rg] + bb;
                if (act) vv = gelu_f(vv);
                if (obf) Cb[(r0 + rg)*(size_t)N + c] = f2bf(vv);
                else     Cf[(r0 + rg)*(size_t)N + c] = vv;
            }
        }
    }
}

// ---------------- 8-phase 256x256 GEMM (Wf logits, K=1024) — R7-proven ----
#define READ_A8(MH, BUF) \
  _Pragma("unroll") for (int mf = 0; mf < 4; ++mf) \
  _Pragma("unroll") for (int kh = 0; kh < 2; ++kh) \
    aA[mf][kh] = *(const s16x8*)&lds[(BUF)*16384 + WR*8192 + (((MH)*4+mf)*128 + (kh*4+fg)*16 + fr)*8];

#define READ_B8(BUF) \
  _Pragma("unroll") for (int nf = 0; nf < 4; ++nf) \
  _Pragma("unroll") for (int kh = 0; kh < 2; ++kh) \
    bB[nf][kh] = *(const s16x8*)&lds[32768 + (BUF)*16384 + BH*8192 + ((BC4+nf)*128 + (kh*4+fg)*16 + fr)*8];

#define QUAD8(MH, NHX) \
  _Pragma("unroll") for (int mf = 0; mf < 4; ++mf) \
  _Pragma("unroll") for (int n2 = 0; n2 < 2; ++n2) { \
    acc[(MH)*4+mf][(NHX)*2+n2] = __builtin_amdgcn_mfma_f32_16x16x32_bf16( \
        aA[mf][0], bB[(NHX)*2+n2][0], acc[(MH)*4+mf][(NHX)*2+n2], 0, 0, 0); \
    acc[(MH)*4+mf][(NHX)*2+n2] = __builtin_amdgcn_mfma_f32_16x16x32_bf16( \
        aA[mf][1], bB[(NHX)*2+n2][1], acc[(MH)*4+mf][(NHX)*2+n2], 0, 0, 0); }

#define STAGE_A8(HH, BUF, KT) { \
    const short* g = pA0 + (HH)*(128*1024) + (KT)*64; \
    short* l = &lds[(BUF)*16384 + (HH)*8192 + tid*8]; \
    gll16(g, l); gll16(g + 64*1024, l + 512*8); }

#define STAGE_B8(HH, BUF, KT) { \
    const short* g = pB0 + (HH)*(128*1024) + (KT)*64; \
    short* l = &lds[32768 + (BUF)*16384 + (HH)*8192 + tid*8]; \
    gll16(g, l); gll16(g + 64*1024, l + 512*8); }

#define PHASE8(BUF, MH, NHX, RA, RB, SMAT, SH, SBUF, SKT, VMW) { \
    if (RA) { READ_A8(MH, BUF) } \
    if (RB) { READ_B8(BUF) } \
    if ((SMAT) == 0) STAGE_A8(SH, SBUF, SKT) else STAGE_B8(SH, SBUF, SKT) \
    __builtin_amdgcn_s_barrier(); \
    asm volatile("s_waitcnt lgkmcnt(0)" ::: "memory"); \
    __builtin_amdgcn_sched_barrier(0); \
    __builtin_amdgcn_s_setprio(1); \
    QUAD8(MH, NHX) \
    __builtin_amdgcn_s_setprio(0); \
    if (VMW) { asm volatile("s_waitcnt vmcnt(4)" ::: "memory"); } \
    __builtin_amdgcn_s_barrier(); }

__global__ __launch_bounds__(512, 2) void gemm8p(
    const short* __restrict__ A, const short* __restrict__ Bt,
    const float* __restrict__ bias, float* __restrict__ C, int N)
{
    extern __shared__ short lds[];
    const int tid  = threadIdx.x;
    const int lane = tid & 63;
    const int wave = tid >> 6;
    const int WR = wave >> 2;
    const int WC = wave & 3;
    const int BH = WC >> 1;
    const int BC4 = (WC & 1) * 4;
    const int fr = lane & 15, fg = lane >> 4;

    const int nwg = gridDim.x;
    const int bid = blockIdx.x;
    const int swz = ((nwg & 7) == 0) ? ((bid & 7) * (nwg >> 3) + (bid >> 3)) : bid;
    const size_t m0 = (size_t)(swz % 8) * 256;
    const size_t n0 = (size_t)(swz / 8) * 256;

    const int arow0 = (tid >> 7) * 16 + (tid & 15);
    const int aks0  = ((tid >> 4) & 7) * 8;
    const short* pA0 = A  + (m0 + arow0) * 1024 + aks0;
    const short* pB0 = Bt + (n0 + arow0) * 1024 + aks0;

    f32x4 acc[8][4] = {};
    s16x8 aA[4][2], bB[4][2];

    STAGE_B8(0, 0, 0) STAGE_B8(1, 0, 0)
    STAGE_A8(0, 0, 0) STAGE_A8(1, 0, 0)
    STAGE_B8(0, 1, 1) STAGE_B8(1, 1, 1)
    asm volatile("s_waitcnt vmcnt(4)" ::: "memory");
    __builtin_amdgcn_s_barrier();

    for (int it = 0; it < 8; ++it) {
        const int k1 = 2*it + 1;
        int k2 = 2*it + 2; if (k2 > 15) k2 = 15;
        int k3 = 2*it + 3; if (k3 > 15) k3 = 15;
        PHASE8(0, 0, 0, 1, 1, 0, 0, 1, k1, 0)
        PHASE8(0, 0, 1, 0, 0, 0, 1, 1, k1, 0)
        PHASE8(0, 1, 0, 1, 0, 1, 0, 0, k2, 0)
        PHASE8(0, 1, 1, 0, 0, 1, 1, 0, k2, 1)
        PHASE8(1, 0, 0, 1, 1, 0, 0, 0, k2, 0)
        PHASE8(1, 0, 1, 0, 0, 0, 1, 0, k2, 0)
        PHASE8(1, 1, 0, 1, 0, 1, 0, 1, k3, 0)
        PHASE8(1, 1, 1, 0, 0, 1, 1, 1, k3, 1)
    }

    #pragma unroll
    for (int mf = 0; mf < 8; ++mf) {
        #pragma unroll
        for (int nf = 0; nf < 4; ++nf) {
            const size_t r0 = m0 + WR*128 + mf*16 + fg*4;
            const size_t c  = n0 + WC*64 + nf*16 + fr;
            const float bb = bias[c];
            #pragma unroll
            for (int rg = 0; rg < 4; ++rg)
                C[(r0 + rg) * (size_t)N + c] = acc[mf][nf][rg] + bb;
        }
    }
}

// ---------------- 2-phase 256x128 GEMM (qkv fused + Qr), 3-buffer ---------
__global__ __launch_bounds__(512, 2) void gemm8n(
    const short* __restrict__ A, const short* __restrict__ Bt,
    const float* __restrict__ bA, const float* __restrict__ bBp,
    const float* __restrict__ bCp, int s1, int s2,
    short* __restrict__ Cb, int N, int K, int nby)
{
    extern __shared__ short lds[];   // A: 3x16384 @0 ; B: 3x8192 @49152
    const int tid  = threadIdx.x;
    const int lane = tid & 63;
    const int wave = tid >> 6;
    const int WR = wave >> 2;
    const int WC = wave & 3;
    const int fr = lane & 15, fg = lane >> 4;

    const int nwg = gridDim.x;
    const int bid = blockIdx.x;
    const int swz = ((nwg & 7) == 0) ? ((bid & 7) * (nwg >> 3) + (bid >> 3)) : bid;
    const size_t m0 = (size_t)(swz % nby) * 256;
    const size_t n0 = (size_t)(swz / nby) * 128;

    const int rA  = (tid >> 7) * 16 + (tid & 15);
    const int ks8 = ((tid >> 4) & 7) * 8;
    const short* pA = A  + (m0 + rA) * (size_t)K + ks8;
    const short* pB = Bt + (n0 + rA) * (size_t)K + ks8;

    auto stageA = [&](int kt, int h, int buf) {
        const short* g = pA + (size_t)(h * 128) * K + kt * 64;
        short* l = &lds[buf * 16384 + h * 8192 + tid * 8];
        gll16(g, l);
        gll16(g + (size_t)64 * K, l + 512 * 8);
    };
    auto stageB = [&](int kt, int buf) {
        const short* g = pB + kt * 64;
        short* l = &lds[49152 + buf * 8192 + tid * 8];
        gll16(g, l);
        gll16(g + (size_t)64 * K, l + 512 * 8);
    };

    f32x4 acc[8][2] = {};
    const int nt = K >> 6;

    stageB(0, 0); stageA(0, 0, 0); stageA(0, 1, 0);
    stageA(1, 0, 1); stageA(1, 1, 1); stageB(1, 1);

    for (int J = 0; J < nt / 2; ++J) {
        const int t0 = 2 * J, t1 = 2 * J + 1;
        const int b0 = t0 % 3, b1 = t1 % 3;
        const int b2 = (t0 + 2) % 3, b3 = (t1 + 2) % 3;
        int s2k = t0 + 2; if (s2k >= nt) s2k = nt - 1;
        int s3k = t1 + 2; if (s3k >= nt) s3k = nt - 1;

        #pragma unroll
        for (int ph = 0; ph < 2; ++ph) {
            const int bt = ph ? b1 : b0;
            asm volatile("s_waitcnt vmcnt(6)" ::: "memory");
            __builtin_amdgcn_s_barrier();
            __builtin_amdgcn_sched_barrier(0);
            if (ph == 0) { stageB(s2k, b2); stageA(s2k, 0, b2); stageA(s2k, 1, b2); }
            else         { stageA(s3k, 0, b3); stageA(s3k, 1, b3); stageB(s3k, b3); }
            s16x8 bB[2][2];
            #pragma unroll
            for (int nf = 0; nf < 2; ++nf)
                #pragma unroll
                for (int kh = 0; kh < 2; ++kh)
                    bB[nf][kh] = *(const s16x8*)&lds[49152 + bt*8192 +
                        ((WC*2 + nf)*128 + (kh*4 + fg)*16 + fr) * 8];
            #pragma unroll
            for (int MH = 0; MH < 2; ++MH) {
                s16x8 aF[4][2];
                #pragma unroll
                for (int mf = 0; mf < 4; ++mf)
                    #pragma unroll
                    for (int kh = 0; kh < 2; ++kh)
                        aF[mf][kh] = *(const s16x8*)&lds[bt*16384 + WR*8192 +
                            ((MH*4 + mf)*128 + (kh*4 + fg)*16 + fr) * 8];
                asm volatile("s_waitcnt lgkmcnt(0)" ::: "memory");
                __builtin_amdgcn_sched_barrier(0);
                __builtin_amdgcn_s_setprio(1);
                #pragma unroll
                for (int mf = 0; mf < 4; ++mf)
                    #pragma unroll
                    for (int nf = 0; nf < 2; ++nf) {
                        acc[MH*4+mf][nf] = __builtin_amdgcn_mfma_f32_16x16x32_bf16(
                            aF[mf][0], bB[nf][0], acc[MH*4+mf][nf], 0, 0, 0);
                        acc[MH*4+mf][nf] = __builtin_amdgcn_mfma_f32_16x16x32_bf16(
                            aF[mf][1], bB[nf][1], acc[MH*4+mf][nf], 0, 0, 0);
                    }
                __builtin_amdgcn_s_setprio(0);
            }
        }
    }

    #pragma unroll
    for (int mf = 0; mf < 8; ++mf) {
        #pragma unroll
        for (int nf = 0; nf < 2; ++nf) {
            const size_t r0 = m0 + WR*128 + mf*16 + fg*4;
            const size_t c  = n0 + WC*32 + nf*16 + fr;
            const float bb = (c < (size_t)s1) ? bA[c]
                            : (c < (size_t)s2) ? bBp[c - s1] : bCp[c - s2];
            #pragma unroll
            for (int rg = 0; rg < 4; ++rg)
                Cb[(r0 + rg) * (size_t)N + c] = f2bf(acc[mf][nf][rg] + bb);
        }
    }
}

// ---------------- weight transpose+convert ----------------
__global__ __launch_bounds__(256) void transpose7_kernel(
    const float* w0, const float* w1, const float* w2, const float* w3,
    const float* w4, const float* w5, const float* w6, short* out)
{
    __shared__ float t[32][33];
    const int z = blockIdx.z;
    const float* W;
    switch (z) {
        case 0: W = w0; break; case 1: W = w1; break; case 2: W = w2; break;
        case 3: W = w3; break; case 4: W = w4; break; case 5: W = w5; break;
        default: W = w6; break;
    }
    short* O = out + (size_t)z * DD * DD;
    const int tid = threadIdx.x;
    const int k0 = blockIdx.y * 32, n0 = blockIdx.x * 32;
    const int r = tid >> 3, c4 = (tid & 7) * 4;
    float4 v = *(const float4*)&W[(size_t)(k0 + r) * DD + n0 + c4];
    t[r][c4+0] = v.x; t[r][c4+1] = v.y; t[r][c4+2] = v.z; t[r][c4+3] = v.w;
    __syncthreads();
    short4 o;
    o.x = f2bf(t[c4+0][r]); o.y = f2bf(t[c4+1][r]);
    o.z = f2bf(t[c4+2][r]); o.w = f2bf(t[c4+3][r]);
    *(short4*)&O[(size_t)(n0 + r) * DD + k0 + c4] = o;
}

__global__ __launch_bounds__(256) void transposeF_kernel(
    const float* __restrict__ W, short* __restrict__ O)
{
    __shared__ float t[32][33];
    const int tid = threadIdx.x;
    const int k0 = blockIdx.y * 32, n0 = blockIdx.x * 32;
    const int r = tid >> 3, c4 = (tid & 7) * 4;
    float4 v = *(const float4*)&W[(size_t)(k0 + r) * VV + n0 + c4];
    t[r][c4+0] = v.x; t[r][c4+1] = v.y; t[r][c4+2] = v.z; t[r][c4+3] = v.w;
    __syncthreads();
    short4 o;
    o.x = f2bf(t[c4+0][r]); o.y = f2bf(t[c4+1][r]);
    o.z = f2bf(t[c4+2][r]); o.w = f2bf(t[c4+3][r]);
    *(short4*)&O[(size_t)(n0 + r) * DD + k0 + c4] = o;
}

// ---------------- MFMA flash attention, QB=64 x KVBLK=128 -----------------
// One barrier-pair per 128 keys (two 64-key compute halves through the same
// wave-exclusive a_t). Qr ring = 192 slots (window 191 wide). Ring-slot
// overwrite safety: the 128 new rows written at iter T+1 replace slots whose
// last reader (iter T) passed barrier A of iter T+1. LDS = 80,896 B ->
// 2 blocks/CU. p_s aliased onto a_t rows (R9, intra-wave lgkm0-fenced).
__global__ __launch_bounds__(256, 2) void attn_kernel(
    const short* __restrict__ q, const short* __restrict__ k,
    const short* __restrict__ v, const short* __restrict__ Qr,
    short* __restrict__ ctx, int kstr, int qstr)
{
    __shared__ short k_s[128][72];
    __shared__ short vT_s[64][136];  // [d][64h + (t64 ^ swz)]
    __shared__ short qr_s[192][72];  // ring: phys = (rb + idx) mod 192
    __shared__ float a_t[64][68];    // scores; p_s aliases row base after softmax

    const int tid  = threadIdx.x;
    const int id   = blockIdx.x;
    const int bh   = id & 31;
    const int qi   = ((id >> 5) + bh) & 15;
    const int q0   = qi * 64;
    const int b    = bh >> 4;
    const int h    = bh & 15;
    const int hoff = h * DH;

    const int lane = tid & 63;
    const int wave = tid >> 6;
    const int fr   = lane & 15;
    const int fg   = lane >> 4;
    // staging maps
    const int tk2 = tid >> 1, ck2 = (tid & 1) * 32;   // k/v: 128 rows x 32 shorts
    const int jq2 = tid >> 1, dqr = (tid & 1) * 32;   // qr:  128 rows x 32 shorts
    const int j2  = tid >> 2, dq2 = (tid & 3) * 16;   // qr init batch2: 64 rows
    // softmax map
    const int sr  = tid >> 2;
    const int sc0 = (tid & 3) * 16;

    const short* qrow = q + ((size_t)(b * TT + q0 + 16 * wave + fr)) * kstr + hoff;
    s16x8 aq0 = *(const s16x8*)(qrow + fg * 8);
    s16x8 aq1 = *(const s16x8*)(qrow + 32 + fg * 8);

    float m_r = -1e30f, l_r = 0.0f;

    const int t_end = q0 + 64 + MEM;
    const int u0b   = SS - 1 - q0 - 63;   // >= 0 for all q0

    s16x8 kf[4], vf[4], rgq[4], rgq2[2];
    auto loadKV = [&](int t0n) {   // rows t0n + tk2 (proved <= 2047 at all call sites)
        const short* kp = k + ((size_t)(b * TT + t0n + tk2)) * kstr + hoff + ck2;
        const short* vp = v + ((size_t)(b * TT + t0n + tk2)) * kstr + hoff + ck2;
        #pragma unroll
        for (int i = 0; i < 4; ++i) {
            kf[i] = *(const s16x8*)(kp + 8 * i);
            vf[i] = *(const s16x8*)(vp + 8 * i);
        }
    };
    auto loadQR = [&](int t0n) {   // new window rows idx 63+jq2 of iter t0n
        int u = t0n + u0b + 63 + jq2;
        u = u > TT - 1 ? TT - 1 : u;   // clamped rows are masked-only
        const short* rp = Qr + (size_t)u * qstr + hoff + dqr;
        #pragma unroll
        for (int i = 0; i < 4; ++i) rgq[i] = *(const s16x8*)(rp + 8 * i);
    };
    {   // init: window(0) idx 0..191 (191 unused garbage row, clamped)
        int u1 = u0b + jq2;
        u1 = u1 > TT - 1 ? TT - 1 : u1;
        const short* rp1 = Qr + (size_t)u1 * qstr + hoff + dqr;
        #pragma unroll
        for (int i = 0; i < 4; ++i) rgq[i] = *(const s16x8*)(rp1 + 8 * i);
        int u2 = u0b + 128 + j2;
        u2 = u2 > TT - 1 ? TT - 1 : u2;
        const short* rp2 = Qr + (size_t)u2 * qstr + hoff + dq2;
        rgq2[0] = *(const s16x8*)rp2;
        rgq2[1] = *(const s16x8*)(rp2 + 8);
    }
    loadKV(0);

    f32x4 opv[4] = {};
    const int nlo = 3 - wave, nhi = 7 - wave;
    int rb = 0;   // ring base = t0 mod 192

    auto computeHalf = [&](int hh, int t0) {
        {   // QK -> a_t
            __builtin_amdgcn_s_setprio(1);
            #pragma unroll
            for (int n = 0; n < 4; ++n) {
                s16x8 b0 = *(const s16x8*)&k_s[64*hh + 16*n + fr][fg * 8];
                s16x8 b1 = *(const s16x8*)&k_s[64*hh + 16*n + fr][32 + fg * 8];
                f32x4 ca = {0, 0, 0, 0};
                ca = __builtin_amdgcn_mfma_f32_16x16x32_bf16(aq0, b0, ca, 0, 0, 0);
                ca = __builtin_amdgcn_mfma_f32_16x16x32_bf16(aq1, b1, ca, 0, 0, 0);
                #pragma unroll
                for (int rg = 0; rg < 4; ++rg)
                    a_t[16*wave + 4*fg + rg][16*n + fr] = ca[rg];
            }
            __builtin_amdgcn_s_setprio(0);
        }
        {   // QR band -> scatter-ADD (ring read, intra-wave rows)
            #pragma unroll
            for (int n = 0; n < 8; ++n) {
                if (n < nlo || n > nhi) continue;   // wave-uniform
                int pr = rb + 64*hh + 16*n + fr;
                if (pr >= 192) pr -= 192;
                s16x8 c0 = *(const s16x8*)&qr_s[pr][fg * 8];
                s16x8 c1 = *(const s16x8*)&qr_s[pr][32 + fg * 8];
                f32x4 cb = {0, 0, 0, 0};
                cb = __builtin_amdgcn_mfma_f32_16x16x32_bf16(aq0, c0, cb, 0, 0, 0);
                cb = __builtin_amdgcn_mfma_f32_16x16x32_bf16(aq1, c1, cb, 0, 0, 0);
                #pragma unroll
                for (int rg = 0; rg < 4; ++rg) {
                    const int r  = 16*wave + 4*fg + rg;
                    const int tl = 16*n + fr - 63 + r;
                    if ((unsigned)tl < 64u) a_t[r][tl] += cb[rg];
                }
            }
        }
        {   // online softmax (intra-wave), P -> bf16 aliased onto a_t rows
            const int sg = q0 + sr;
            const int tb = t0 + 64*hh;
            float e[16];
            float mx = -1e30f;
            #pragma unroll
            for (int j = 0; j < 16; ++j) {
                const int c = sc0 + j;
                float x = a_t[sr][c] * 0.125f;
                x = (tb + c > sg + MEM) ? -1e30f : x;
                e[j] = x;
                mx = fmaxf(mx, x);
            }
            mx = fmaxf(mx, __shfl_xor(mx, 1, 64));
            mx = fmaxf(mx, __shfl_xor(mx, 2, 64));
            const float mn  = fmaxf(m_r, mx);
            const float scl = __expf(m_r - mn);
            float sum = 0.0f;
            s16x8 p0, p1;
            #pragma unroll
            for (int j = 0; j < 16; ++j) {
                float ev = __expf(e[j] - mn);
                sum += ev;
                if (j < 8) p0[j] = f2bf(ev); else p1[j - 8] = f2bf(ev);
            }
            sum += __shfl_xor(sum, 1, 64);
            sum += __shfl_xor(sum, 2, 64);
            l_r = l_r * scl + sum;
            m_r = mn;
            short* prow = (short*)&a_t[sr][0];
            *(s16x8*)&prow[sc0]     = p0;
            *(s16x8*)&prow[sc0 + 8] = p1;
            asm volatile("s_waitcnt lgkmcnt(0)" ::: "memory");   // p visible intra-wave
            __builtin_amdgcn_sched_barrier(0);

            // PV: rescale acc, then acc += P @ V
            f32x4 scv;
            #pragma unroll
            for (int rg = 0; rg < 4; ++rg) scv[rg] = __shfl(scl, 16*fg + 4*rg, 64);
            #pragma unroll
            for (int n = 0; n < 4; ++n)
                #pragma unroll
                for (int rg = 0; rg < 4; ++rg) opv[n][rg] *= scv[rg];
            const short* pv = (const short*)&a_t[16*wave + fr][0];
            s16x8 ap0 = *(const s16x8*)&pv[fg * 8];
            s16x8 ap1 = *(const s16x8*)&pv[32 + fg * 8];
            __builtin_amdgcn_s_setprio(1);
            #pragma unroll
            for (int n = 0; n < 4; ++n) {
                const int d  = 16*n + fr;
                const int xw = (d >> 3) & 3;
                s16x8 bv0 = *(const s16x8*)&vT_s[d][64*hh + (fg ^ xw) * 8];
                s16x8 bv1 = *(const s16x8*)&vT_s[d][64*hh + 32 + ((fg + 4) ^ xw ? 0 : 0) + (fg ^ xw) * 8 - (fg ^ xw) * 8 + ((fg ^ xw) * 8)];
                // NOTE: bv1 covers k-slices 32..63 of this half: column base +32
                bv1 = *(const s16x8*)&vT_s[d][64*hh + 32 + (fg ^ xw) * 8];
                opv[n] = __builtin_amdgcn_mfma_f32_16x16x32_bf16(ap0, bv0, opv[n], 0, 0, 0);
                opv[n] = __builtin_amdgcn_mfma_f32_16x16x32_bf16(ap1, bv1, opv[n], 0, 0, 0);
            }
            __builtin_amdgcn_s_setprio(0);
        }
    };

    for (int t0 = 0; t0 < t_end; t0 += 128) {
        asm volatile("" ::: "memory");
        __builtin_amdgcn_s_barrier();        // barrier A: prev iter's reads retired
        __builtin_amdgcn_sched_barrier(0);
        {   // staged regs -> LDS (128 k/v rows; 128 new qr rows, or 192 at init)
            #pragma unroll
            for (int i = 0; i < 4; ++i)
                *(s16x8*)&k_s[tk2][ck2 + 8*i] = kf[i];
            #pragma unroll
            for (int i = 0; i < 4; ++i) {
                #pragma unroll
                for (int e = 0; e < 8; ++e) {
                    const int d = ck2 + 8*i + e;
                    const int col = 64*(tk2 >> 6) + ((tk2 & 63) ^ (((d >> 3) & 3) << 3));
                    vT_s[d][col] = vf[i][e];
                }
            }
            if (t0 == 0) {
                #pragma unroll
                for (int i = 0; i < 4; ++i)
                    *(s16x8*)&qr_s[jq2][dqr + 8*i] = rgq[i];
                *(s16x8*)&qr_s[128 + j2][dq2]     = rgq2[0];
                *(s16x8*)&qr_s[128 + j2][dq2 + 8] = rgq2[1];
            } else {
                int p = rb + 63 + jq2;
                if (p >= 192) p -= 192;
                #pragma unroll
                for (int i = 0; i < 4; ++i)
                    *(s16x8*)&qr_s[p][dqr + 8*i] = rgq[i];
            }
        }
        if (t0 + 128 < t_end) { loadKV(t0 + 128); loadQR(t0 + 128); }   // T14
        asm volatile("s_waitcnt lgkmcnt(0)" ::: "memory");
        __builtin_amdgcn_s_barrier();        // barrier B: LDS visible; vmcnt NOT drained
        __builtin_amdgcn_sched_barrier(0);

        computeHalf(0, t0);
        if (t0 + 64 < t_end) computeHalf(1, t0);

        rb += 128; if (rb >= 192) rb -= 192;
    }

    {   // epilogue
        f32x4 lv;
        #pragma unroll
        for (int rg = 0; rg < 4; ++rg) lv[rg] = __shfl(l_r, 16*fg + 4*rg, 64);
        #pragma unroll
        for (int rg = 0; rg < 4; ++rg) {
            const int r = 16*wave + 4*fg + rg;
            const float inv = 1.0f / lv[rg];
            short* op = ctx + ((size_t)(b * SS + q0 + r)) * DD + hoff;
            #pragma unroll
            for (int n = 0; n < 4; ++n)
                op[16*n + fr] = f2bf(opv[n][rg] * inv);
        }
    }
}

// ---------------- add + LayerNorm, dual f32 + bf16 output ----------------
__global__ __launch_bounds__(256) void addln_kernel(
    const float* __restrict__ a, const float* __restrict__ b,
    const float* __restrict__ g, const float* __restrict__ be,
    float* __restrict__ out32, short* __restrict__ outbf)
{
    __shared__ float red[8];
    const int row = blockIdx.x;
    const int tid = threadIdx.x;
    const size_t base = (size_t)row * DD;
    const int c = tid * 4;
    float4 xa = *(const float4*)(a + base + c);
    float4 xb = *(const float4*)(b + base + c);
    float x0 = xa.x + xb.x, x1 = xa.y + xb.y, x2 = xa.z + xb.z, x3 = xa.w + xb.w;
    float s  = x0 + x1 + x2 + x3;
    float sq = x0 * x0 + x1 * x1 + x2 * x2 + x3 * x3;
    #pragma unroll
    for (int o = 32; o > 0; o >>= 1) {
        s  += __shfl_down(s, o, 64);
        sq += __shfl_down(sq, o, 64);
    }
    const int wv = tid >> 6;
    if ((tid & 63) == 0) { red[wv * 2] = s; red[wv * 2 + 1] = sq; }
    __syncthreads();
    float ts = red[0] + red[2] + red[4] + red[6];
    float tq = red[1] + red[3] + red[5] + red[7];
    float mu  = ts * (1.0f / DD);
    float var = tq * (1.0f / DD) - mu * mu;
    float rs  = rsqrtf(var + 1e-5f);
    float4 gv = *(const float4*)(g + c);
    float4 bv = *(const float4*)(be + c);
    float4 o4;
    o4.x = (x0 - mu) * rs * gv.x + bv.x;
    o4.y = (x1 - mu) * rs * gv.y + bv.y;
    o4.z = (x2 - mu) * rs * gv.z + bv.z;
    o4.w = (x3 - mu) * rs * gv.w + bv.w;
    *(float4*)(out32 + base + c) = o4;
    short4 ob;
    ob.x = f2bf(o4.x); ob.y = f2bf(o4.y); ob.z = f2bf(o4.z); ob.w = f2bf(o4.w);
    *(short4*)(outbf + base + c) = ob;
}

// ---------------- embedding gather * sqrt(D), dual output ----------------
__global__ __launch_bounds__(256) void embed_kernel(
    const int* __restrict__ inp, const float* __restrict__ emb,
    float* __restrict__ x32, short* __restrict__ xbf)
{
    const int row = blockIdx.x;
    const int c = threadIdx.x * 4;
    const int idx = inp[row];
    float4 vv = *(const float4*)(emb + (size_t)idx * DD + c);
    vv.x *= 32.0f; vv.y *= 32.0f; vv.z *= 32.0f; vv.w *= 32.0f;
    *(float4*)(x32 + (size_t)row * DD + c) = vv;
    short4 ob;
    ob.x = f2bf(vv.x); ob.y = f2bf(vv.y); ob.z = f2bf(vv.z); ob.w = f2bf(vv.w);
    *(short4*)(xbf + (size_t)row * DD + c) = ob;
}

// ---------------- concat mems[l] (f32) and x (bf16) -> xt (bf16) ----------
__global__ __launch_bounds__(256) void concat_kernel(
    const float* __restrict__ mems_l, const short* __restrict__ xbf,
    short* __restrict__ xt)
{
    size_t i = ((size_t)blockIdx.x * 256 + threadIdx.x) * 8;
    size_t bt = i / DD;
    int d = (int)(i - bt * DD);
    int b = (int)(bt / TT);
    int t = (int)(bt - (size_t)b * TT);
    s16x8 o;
    if (t < MEM) {
        const float* mp = mems_l + ((size_t)(b * MEM + t)) * DD + d;
        float4 a0 = *(const float4*)mp;
        float4 a1 = *(const float4*)(mp + 4);
        o[0] = f2bf(a0.x); o[1] = f2bf(a0.y); o[2] = f2bf(a0.z); o[3] = f2bf(a0.w);
        o[4] = f2bf(a1.x); o[5] = f2bf(a1.y); o[6] = f2bf(a1.z); o[7] = f2bf(a1.w);
    } else {
        o = *(const s16x8*)(xbf + ((size_t)(b * SS + (t - MEM))) * DD + d);
    }
    *(s16x8*)(xt + i) = o;
}

// ---------------- reversed sinusoidal position encoding (bf16) ------------
__global__ __launch_bounds__(256) void relenc_kernel(short* __restrict__ re)
{
    const int u = blockIdx.x;
    const int p = TT - 1 - u;
    const int i0 = threadIdx.x * 4;
    short4 o;
    #pragma unroll
    for (int j = 0; j < 4; ++j) {
        int i = i0 + j;
        float ex   = (float)(2 * (i >> 1)) * (1.0f / DD);
        float invf = __expf(-ex * 9.210340371976184f);
        float ang  = (float)p * invf;
        float val  = (i & 1) ? cosf(ang) : sinf(ang);
        ((short*)&o)[j] = f2bf(val);
    }
    *(short4*)&re[(size_t)u * DD + i0] = o;
}

extern "C" void kernel_launch(void* const* d_in, const int* in_sizes, int n_in,
                              void* d_out, int out_size, void* d_ws, size_t ws_size,
                              hipStream_t stream)
{
    const int*   inp  = (const int*)d_in[0];
    const float* mems = (const float*)d_in[1];
    const float* emb  = (const float*)d_in[2];
    const float* Wq   = (const float*)d_in[3];
    const float* bq   = (const float*)d_in[4];
    const float* Wke  = (const float*)d_in[5];
    const float* bke  = (const float*)d_in[6];
    const float* Wkr  = (const float*)d_in[7];
    const float* bkr  = (const float*)d_in[8];
    const float* Wv   = (const float*)d_in[9];
    const float* bv   = (const float*)d_in[10];
    const float* Wo   = (const float*)d_in[11];
    const float* bo   = (const float*)d_in[12];
    const float* ln1g = (const float*)d_in[13];
    const float* ln1b = (const float*)d_in[14];
    const float* W1   = (const float*)d_in[15];
    const float* b1   = (const float*)d_in[16];
    const float* W2   = (const float*)d_in[17];
    const float* b2   = (const float*)d_in[18];
    const float* ln2g = (const float*)d_in[19];
    const float* ln2b = (const float*)d_in[20];
    const float* Wh   = (const float*)d_in[21];
    const float* bh   = (const float*)d_in[22];
    const float* Wf   = (const float*)d_in[23];
    const float* bfb  = (const float*)d_in[24];

    hipFuncSetAttribute((const void*)gemm8p,
                        hipFuncAttributeMaxDynamicSharedMemorySize, 131072);
    hipFuncSetAttribute((const void*)gemm8n,
                        hipFuncAttributeMaxDynamicSharedMemorySize, 147456);

    char* wsb = (char*)d_ws;
    size_t off = 0;
    auto alloc = [&](size_t bytes) { char* p = wsb + off; off += (bytes + 255) & ~(size_t)255; return p; };
    float* h132  = (float*)alloc((size_t)BB*SS*DD*4);
    float* ao32  = (float*)alloc((size_t)BB*SS*DD*4);
    float* ff232 = (float*)alloc((size_t)BB*SS*DD*4);
    short* xt    = (short*)alloc((size_t)BB*TT*DD*2);
    short* qkvb  = (short*)alloc((size_t)BB*TT*3*DD*2);   // [B*T][3072]: q|k|v
    short* ctxb  = (short*)alloc((size_t)BB*SS*DD*2);
    short* ff1   = (short*)alloc((size_t)BB*SS*DD*2);
    // end transient (~73 MB); aliased by wkr4 (pre-loop) and wft (post-loop)
    float* x32   = (float*)alloc((size_t)BB*SS*DD*4);
    short* x_bf  = (short*)alloc((size_t)BB*SS*DD*2);
    short* whout = (short*)alloc((size_t)BB*SS*DD*2);
    short* rel   = (short*)alloc((size_t)TT*DD*2);
    short* qr4   = (short*)alloc((size_t)TT*4*DD*2);      // [2048][4096] bf16
    short* wt6   = (short*)alloc((size_t)6*DD*DD*2);
    short* wkr4  = (short*)h132;
    short* wft   = (short*)h132;

    relenc_kernel<<<TT, 256, 0, stream>>>(rel);
    embed_kernel<<<BB * SS, 256, 0, stream>>>(inp, emb, x32, x_bf);

    const size_t WOFF = (size_t)DD * DD;

    // hoisted: Qr all layers = rel @ [Wkr0^T|..|Wkr3^T]; bias = bkr (L,D) flat
    transpose7_kernel<<<dim3(32, 32, 4), 256, 0, stream>>>(
        Wkr + 0*WOFF, Wkr + 1*WOFF, Wkr + 2*WOFF, Wkr + 3*WOFF, Wq, Wq, Wq, wkr4);
    gemm8n<<<dim3((TT/256) * (4*DD/128)), 512, 147456, stream>>>(
        rel, wkr4, bkr, bkr, bkr, 4*DD, 4*DD, qr4, 4*DD, DD, TT/256);

    const int gSm = (DD / 64) * ((BB * SS) / 64);   // 512 blocks, 64x64 tiles

    for (int l = 0; l < LL; ++l) {
        const size_t wo  = (size_t)l * DD * DD;
        const size_t bo_ = (size_t)l * DD;
        transpose7_kernel<<<dim3(32, 32, 6), 256, 0, stream>>>(
            Wq + wo, Wke + wo, Wv + wo, Wo + wo, W1 + wo, W2 + wo, Wq, wt6);
        concat_kernel<<<(BB * TT * DD / 8) / 256, 256, 0, stream>>>(
            mems + (size_t)l * BB * MEM * DD, x_bf, xt);
        gemm8n<<<dim3((BB*TT/256) * (3*DD/128)), 512, 147456, stream>>>(
            xt, wt6, bq + bo_, bke + bo_, bv + bo_, DD, 2*DD, qkvb, 3*DD, DD, BB*TT/256);
        attn_kernel<<<dim3((SS / 64) * BB * NH), 256, 0, stream>>>(
            qkvb + (size_t)MEM * 3 * DD, qkvb + DD, qkvb + 2 * DD,
            qr4 + (size_t)l * DD, ctxb, 3 * DD, 4 * DD);
        gemm_k128<2,2><<<dim3(gSm), 256, 0, stream>>>(
            ctxb, wt6 + 3*WOFF, bo + bo_, bo + bo_, DD, ao32, DD, DD, (BB*SS)/64, 0, 0);
        addln_kernel<<<BB * SS, 256, 0, stream>>>(x32, ao32, ln1g + bo_, ln1b + bo_, h132, x_bf);
        gemm_k128<2,2><<<dim3(gSm), 256, 0, stream>>>(
            x_bf, wt6 + 4*WOFF, b1 + bo_, b1 + bo_, DD, ff1, DD, DD, (BB*SS)/64, 1, 1);
        gemm_k128<2,2><<<dim3(gSm), 256, 0, stream>>>(
            ff1, wt6 + 5*WOFF, b2 + bo_, b2 + bo_, DD, ff232, DD, DD, (BB*SS)/64, 0, 0);
        addln_kernel<<<BB * SS, 256, 0, stream>>>(h132, ff232, ln2g + bo_, ln2b + bo_, x32, x_bf);
    }

    transpose7_kernel<<<dim3(32, 32, 1), 256, 0, stream>>>(
        Wh, Wh, Wh, Wh, Wh, Wh, Wh, wt6);
    transposeF_kernel<<<dim3(VV / 32, DD / 32), 256, 0, stream>>>(Wf, wft);
    gemm_k128<2,2><<<dim3(gSm), 256, 0, stream>>>(
        x_bf, wt6, bh, bh, DD, whout, DD, DD, (BB*SS)/64, 1, 1);
    gemm8p<<<dim3((VV / 256) * ((BB * SS) / 256)), 512, 131072, stream>>>(
        whout, wft, bfb, (float*)d_out, VV);
}

// Round 13
// 1256.424 us; speedup vs baseline: 1.0083x; 1.0083x over previous
//
#include <hip/hip_runtime.h>
#include <hip/hip_bf16.h>
#include <math.h>

typedef __attribute__((ext_vector_type(4))) float f32x4;
typedef __attribute__((ext_vector_type(8))) short s16x8;

#define BB 2
#define SS 1024
#define MEM 1024
#define DD 1024
#define LL 4
#define VV 32000
#define TT 2048
#define NH 16
#define DH 64

__device__ __forceinline__ short f2bf(float f) {
    unsigned u = __float_as_uint(f);
    u += 0x7fffu + ((u >> 16) & 1u);   // round-to-nearest-even
    return (short)(u >> 16);
}

__device__ __forceinline__ float gelu_f(float x) {
    return 0.5f * x * (1.0f + erff(x * 0.70710678118654752f));
}

__device__ __forceinline__ void gll16(const short* g, short* l) {
    __builtin_amdgcn_global_load_lds(
        (__attribute__((address_space(1))) void*)(short*)g,
        (__attribute__((address_space(3))) void*)l, 16, 0, 0);
}

// ---------------- GEMM small-shape: BK=128, 2-barrier (R5 structure) -------
template<int WM, int WN>
__global__ __launch_bounds__(256) void gemm_k128(
    const short* __restrict__ A, const short* __restrict__ Bt,
    const float* __restrict__ bias, const float* __restrict__ bias2,
    int nsplit, void* __restrict__ Cv, int N, int K, int nby, int act, int obf)
{
    constexpr int BM = WM * 32, BN = WN * 32;
    constexpr int NA = BM / 16, NB = BN / 16;
    __shared__ short a_s[BM * 128];
    __shared__ short b_s[BN * 128];
    const int tid  = threadIdx.x;
    const int lane = tid & 63;
    const int wave = tid >> 6;
    const int wr = wave >> 1, wc = wave & 1;
    const int fr = lane & 15, fg = lane >> 4;

    const int nwg = gridDim.x;
    const int bid = blockIdx.x;
    const int swz = ((nwg & 7) == 0) ? ((bid & 7) * (nwg >> 3) + (bid >> 3)) : bid;
    const size_t m0 = (size_t)(swz % nby) * BM;
    const size_t n0 = (size_t)(swz / nby) * BN;

    const short* gA[NA]; short* lA[NA];
    const short* gB[NB]; short* lB[NB];
    #pragma unroll
    for (int i = 0; i < NA; ++i) {
        gA[i] = A + (m0 + i * 16 + (tid & 15)) * (size_t)K + (tid >> 4) * 8;
        lA[i] = &a_s[(i * 256 + tid) * 8];
    }
    #pragma unroll
    for (int i = 0; i < NB; ++i) {
        gB[i] = Bt + (n0 + i * 16 + (tid & 15)) * (size_t)K + (tid >> 4) * 8;
        lB[i] = &b_s[(i * 256 + tid) * 8];
    }

    f32x4 acc[WM][WN] = {};

    #pragma unroll
    for (int i = 0; i < NA; ++i) gll16(gA[i], lA[i]);
    #pragma unroll
    for (int i = 0; i < NB; ++i) gll16(gB[i], lB[i]);

    const int nt = K >> 7;
    for (int t = 0; t < nt; ++t) {
        __syncthreads();
        s16x8 af[WM][4], bf[WN][4];
        #pragma unroll
        for (int mi = 0; mi < WM; ++mi)
            #pragma unroll
            for (int h = 0; h < 4; ++h)
                af[mi][h] = *(const s16x8*)&a_s[((wr*WM + mi)*256 + (4*h + fg)*16 + fr) * 8];
        #pragma unroll
        for (int ni = 0; ni < WN; ++ni)
            #pragma unroll
            for (int h = 0; h < 4; ++h)
                bf[ni][h] = *(const s16x8*)&b_s[((wc*WN + ni)*256 + (4*h + fg)*16 + fr) * 8];
        if (t + 1 < nt) {
            __syncthreads();
            const int koff = (t + 1) << 7;
            #pragma unroll
            for (int i = 0; i < NA; ++i) gll16(gA[i] + koff, lA[i]);
            #pragma unroll
            for (int i = 0; i < NB; ++i) gll16(gB[i] + koff, lB[i]);
        }
        #pragma unroll
        for (int mi = 0; mi < WM; ++mi)
            #pragma unroll
            for (int ni = 0; ni < WN; ++ni)
                #pragma unroll
                for (int h = 0; h < 4; ++h)
                    acc[mi][ni] = __builtin_amdgcn_mfma_f32_16x16x32_bf16(
                        af[mi][h], bf[ni][h], acc[mi][ni], 0, 0, 0);
    }

    float* Cf = (float*)Cv;
    short* Cb = (short*)Cv;
    #pragma unroll
    for (int mi = 0; mi < WM; ++mi) {
        #pragma unroll
        for (int ni = 0; ni < WN; ++ni) {
            const size_t r0 = m0 + wr*WM*16 + mi*16 + fg*4;
            const size_t c  = n0 + wc*WN*16 + ni*16 + fr;
            const float bb = (c < (size_t)nsplit) ? bias[c] : bias2[c - nsplit];
            #pragma unroll
            for (int rg = 0; rg < 4; ++rg) {
                float vv = acc[mi][ni][rg] + bb;
                if (act) vv = gelu_f(vv);
                if (obf) Cb[(r0 + rg)*(size_t)N + c] = f2bf(vv);
                else     Cf[(r0 + rg)*(size_t)N + c] = vv;
            }
        }
    }
}

// ---------------- 8-phase 256x256 GEMM (Wf logits, K=1024) — R7-proven ----
#define READ_A8(MH, BUF) \
  _Pragma("unroll") for (int mf = 0; mf < 4; ++mf) \
  _Pragma("unroll") for (int kh = 0; kh < 2; ++kh) \
    aA[mf][kh] = *(const s16x8*)&lds[(BUF)*16384 + WR*8192 + (((MH)*4+mf)*128 + (kh*4+fg)*16 + fr)*8];

#define READ_B8(BUF) \
  _Pragma("unroll") for (int nf = 0; nf < 4; ++nf) \
  _Pragma("unroll") for (int kh = 0; kh < 2; ++kh) \
    bB[nf][kh] = *(const s16x8*)&lds[32768 + (BUF)*16384 + BH*8192 + ((BC4+nf)*128 + (kh*4+fg)*16 + fr)*8];

#define QUAD8(MH, NHX) \
  _Pragma("unroll") for (int mf = 0; mf < 4; ++mf) \
  _Pragma("unroll") for (int n2 = 0; n2 < 2; ++n2) { \
    acc[(MH)*4+mf][(NHX)*2+n2] = __builtin_amdgcn_mfma_f32_16x16x32_bf16( \
        aA[mf][0], bB[(NHX)*2+n2][0], acc[(MH)*4+mf][(NHX)*2+n2], 0, 0, 0); \
    acc[(MH)*4+mf][(NHX)*2+n2] = __builtin_amdgcn_mfma_f32_16x16x32_bf16( \
        aA[mf][1], bB[(NHX)*2+n2][1], acc[(MH)*4+mf][(NHX)*2+n2], 0, 0, 0); }

#define STAGE_A8(HH, BUF, KT) { \
    const short* g = pA0 + (HH)*(128*1024) + (KT)*64; \
    short* l = &lds[(BUF)*16384 + (HH)*8192 + tid*8]; \
    gll16(g, l); gll16(g + 64*1024, l + 512*8); }

#define STAGE_B8(HH, BUF, KT) { \
    const short* g = pB0 + (HH)*(128*1024) + (KT)*64; \
    short* l = &lds[32768 + (BUF)*16384 + (HH)*8192 + tid*8]; \
    gll16(g, l); gll16(g + 64*1024, l + 512*8); }

#define PHASE8(BUF, MH, NHX, RA, RB, SMAT, SH, SBUF, SKT, VMW) { \
    if (RA) { READ_A8(MH, BUF) } \
    if (RB) { READ_B8(BUF) } \
    if ((SMAT) == 0) STAGE_A8(SH, SBUF, SKT) else STAGE_B8(SH, SBUF, SKT) \
    __builtin_amdgcn_s_barrier(); \
    asm volatile("s_waitcnt lgkmcnt(0)" ::: "memory"); \
    __builtin_amdgcn_sched_barrier(0); \
    __builtin_amdgcn_s_setprio(1); \
    QUAD8(MH, NHX) \
    __builtin_amdgcn_s_setprio(0); \
    if (VMW) { asm volatile("s_waitcnt vmcnt(4)" ::: "memory"); } \
    __builtin_amdgcn_s_barrier(); }

__global__ __launch_bounds__(512, 2) void gemm8p(
    const short* __restrict__ A, const short* __restrict__ Bt,
    const float* __restrict__ bias, float* __restrict__ C, int N)
{
    extern __shared__ short lds[];
    const int tid  = threadIdx.x;
    const int lane = tid & 63;
    const int wave = tid >> 6;
    const int WR = wave >> 2;
    const int WC = wave & 3;
    const int BH = WC >> 1;
    const int BC4 = (WC & 1) * 4;
    const int fr = lane & 15, fg = lane >> 4;

    const int nwg = gridDim.x;
    const int bid = blockIdx.x;
    const int swz = ((nwg & 7) == 0) ? ((bid & 7) * (nwg >> 3) + (bid >> 3)) : bid;
    const size_t m0 = (size_t)(swz % 8) * 256;
    const size_t n0 = (size_t)(swz / 8) * 256;

    const int arow0 = (tid >> 7) * 16 + (tid & 15);
    const int aks0  = ((tid >> 4) & 7) * 8;
    const short* pA0 = A  + (m0 + arow0) * 1024 + aks0;
    const short* pB0 = Bt + (n0 + arow0) * 1024 + aks0;

    f32x4 acc[8][4] = {};
    s16x8 aA[4][2], bB[4][2];

    STAGE_B8(0, 0, 0) STAGE_B8(1, 0, 0)
    STAGE_A8(0, 0, 0) STAGE_A8(1, 0, 0)
    STAGE_B8(0, 1, 1) STAGE_B8(1, 1, 1)
    asm volatile("s_waitcnt vmcnt(4)" ::: "memory");
    __builtin_amdgcn_s_barrier();

    for (int it = 0; it < 8; ++it) {
        const int k1 = 2*it + 1;
        int k2 = 2*it + 2; if (k2 > 15) k2 = 15;
        int k3 = 2*it + 3; if (k3 > 15) k3 = 15;
        PHASE8(0, 0, 0, 1, 1, 0, 0, 1, k1, 0)
        PHASE8(0, 0, 1, 0, 0, 0, 1, 1, k1, 0)
        PHASE8(0, 1, 0, 1, 0, 1, 0, 0, k2, 0)
        PHASE8(0, 1, 1, 0, 0, 1, 1, 0, k2, 1)
        PHASE8(1, 0, 0, 1, 1, 0, 0, 0, k2, 0)
        PHASE8(1, 0, 1, 0, 0, 0, 1, 0, k2, 0)
        PHASE8(1, 1, 0, 1, 0, 1, 0, 1, k3, 0)
        PHASE8(1, 1, 1, 0, 0, 1, 1, 1, k3, 1)
    }

    #pragma unroll
    for (int mf = 0; mf < 8; ++mf) {
        #pragma unroll
        for (int nf = 0; nf < 4; ++nf) {
            const size_t r0 = m0 + WR*128 + mf*16 + fg*4;
            const size_t c  = n0 + WC*64 + nf*16 + fr;
            const float bb = bias[c];
            #pragma unroll
            for (int rg = 0; rg < 4; ++rg)
                C[(r0 + rg) * (size_t)N + c] = acc[mf][nf][rg] + bb;
        }
    }
}

// ---------------- 2-phase 256x128 GEMM, 3-buffer, split-A + trimmed grid --
// mapmode 0: standard nby m-fastest map, single A source (Am).
// mapmode 1 (qkv): 320-block map — q n-tiles (0..7) x 8 x-row m-tiles
// {4..7,12..15}; k/v n-tiles (8..23) x all 16 m-tiles. A source per 256-row
// M-tile (1024-aligned regions): mem rows -> Am, x rows -> Ax.
__global__ __launch_bounds__(512, 2) void gemm8n(
    const short* __restrict__ Am, const short* __restrict__ Ax,
    const short* __restrict__ Bt,
    const float* __restrict__ bA, const float* __restrict__ bBp,
    const float* __restrict__ bCp, int s1, int s2,
    short* __restrict__ Cb, int N, int K, int nby, int mapmode)
{
    extern __shared__ short lds[];   // A: 3x16384 @0 ; B: 3x8192 @49152
    const int tid  = threadIdx.x;
    const int lane = tid & 63;
    const int wave = tid >> 6;
    const int WR = wave >> 2;
    const int WC = wave & 3;
    const int fr = lane & 15, fg = lane >> 4;

    const int nwg = gridDim.x;
    const int bid = blockIdx.x;
    const int swz = ((nwg & 7) == 0) ? ((bid & 7) * (nwg >> 3) + (bid >> 3)) : bid;

    size_t m0, n0;
    if (mapmode == 0) {
        m0 = (size_t)(swz % nby) * 256;
        n0 = (size_t)(swz / nby) * 128;
    } else {
        int mt, ntile;
        if (swz < 64) {   // q columns: only x-row m-tiles {4..7, 12..15}
            ntile = swz >> 3;
            int mi = swz & 7;
            mt = (mi & 3) + 4 + (mi >> 2) * 8;
        } else {          // k,v columns: all 16 m-tiles (identity map)
            int j = swz - 64;
            ntile = 8 + (j >> 4);
            mt = j & 15;   // FIXED (R11 bug: old formula produced mt up to 27)
        }
        m0 = (size_t)mt * 256;
        n0 = (size_t)ntile * 128;
    }

    const short* Abase; size_t row0;
    if (mapmode == 1) {
        const int bb = (int)(m0 >> 11), t = (int)(m0 & 2047);
        if (t < 1024) { Abase = Am; row0 = (size_t)(bb * 1024 + t); }
        else          { Abase = Ax; row0 = (size_t)(bb * 1024 + t - 1024); }
    } else { Abase = Am; row0 = m0; }

    const int rA  = (tid >> 7) * 16 + (tid & 15);
    const int ks8 = ((tid >> 4) & 7) * 8;
    const short* pA = Abase + (row0 + rA) * (size_t)K + ks8;
    const short* pB = Bt + (n0 + rA) * (size_t)K + ks8;

    auto stageA = [&](int kt, int h, int buf) {
        const short* g = pA + (size_t)(h * 128) * K + kt * 64;
        short* l = &lds[buf * 16384 + h * 8192 + tid * 8];
        gll16(g, l);
        gll16(g + (size_t)64 * K, l + 512 * 8);
    };
    auto stageB = [&](int kt, int buf) {
        const short* g = pB + kt * 64;
        short* l = &lds[49152 + buf * 8192 + tid * 8];
        gll16(g, l);
        gll16(g + (size_t)64 * K, l + 512 * 8);
    };

    f32x4 acc[8][2] = {};
    const int nt = K >> 6;

    stageB(0, 0); stageA(0, 0, 0); stageA(0, 1, 0);
    stageA(1, 0, 1); stageA(1, 1, 1); stageB(1, 1);

    for (int J = 0; J < nt / 2; ++J) {
        const int t0 = 2 * J, t1 = 2 * J + 1;
        const int b0 = t0 % 3, b1 = t1 % 3;
        const int b2 = (t0 + 2) % 3, b3 = (t1 + 2) % 3;
        int s2k = t0 + 2; if (s2k >= nt) s2k = nt - 1;
        int s3k = t1 + 2; if (s3k >= nt) s3k = nt - 1;

        #pragma unroll
        for (int ph = 0; ph < 2; ++ph) {
            const int bt = ph ? b1 : b0;
            asm volatile("s_waitcnt vmcnt(6)" ::: "memory");
            __builtin_amdgcn_s_barrier();
            __builtin_amdgcn_sched_barrier(0);
            if (ph == 0) { stageB(s2k, b2); stageA(s2k, 0, b2); stageA(s2k, 1, b2); }
            else         { stageA(s3k, 0, b3); stageA(s3k, 1, b3); stageB(s3k, b3); }
            s16x8 bB[2][2];
            #pragma unroll
            for (int nf = 0; nf < 2; ++nf)
                #pragma unroll
                for (int kh = 0; kh < 2; ++kh)
                    bB[nf][kh] = *(const s16x8*)&lds[49152 + bt*8192 +
                        ((WC*2 + nf)*128 + (kh*4 + fg)*16 + fr) * 8];
            #pragma unroll
            for (int MH = 0; MH < 2; ++MH) {
                s16x8 aF[4][2];
                #pragma unroll
                for (int mf = 0; mf < 4; ++mf)
                    #pragma unroll
                    for (int kh = 0; kh < 2; ++kh)
                        aF[mf][kh] = *(const s16x8*)&lds[bt*16384 + WR*8192 +
                            ((MH*4 + mf)*128 + (kh*4 + fg)*16 + fr) * 8];
                asm volatile("s_waitcnt lgkmcnt(0)" ::: "memory");
                __builtin_amdgcn_sched_barrier(0);
                __builtin_amdgcn_s_setprio(1);
                #pragma unroll
                for (int mf = 0; mf < 4; ++mf)
                    #pragma unroll
                    for (int nf = 0; nf < 2; ++nf) {
                        acc[MH*4+mf][nf] = __builtin_amdgcn_mfma_f32_16x16x32_bf16(
                            aF[mf][0], bB[nf][0], acc[MH*4+mf][nf], 0, 0, 0);
                        acc[MH*4+mf][nf] = __builtin_amdgcn_mfma_f32_16x16x32_bf16(
                            aF[mf][1], bB[nf][1], acc[MH*4+mf][nf], 0, 0, 0);
                    }
                __builtin_amdgcn_s_setprio(0);
            }
        }
    }

    #pragma unroll
    for (int mf = 0; mf < 8; ++mf) {
        #pragma unroll
        for (int nf = 0; nf < 2; ++nf) {
            const size_t r0 = m0 + WR*128 + mf*16 + fg*4;
            const size_t c  = n0 + WC*32 + nf*16 + fr;
            const float bb = (c < (size_t)s1) ? bA[c]
                            : (c < (size_t)s2) ? bBp[c - s1] : bCp[c - s2];
            #pragma unroll
            for (int rg = 0; rg < 4; ++rg)
                Cb[(r0 + rg) * (size_t)N + c] = f2bf(acc[mf][nf][rg] + bb);
        }
    }
}

// ---------------- weight transpose+convert ----------------
__global__ __launch_bounds__(256) void transpose7_kernel(
    const float* w0, const float* w1, const float* w2, const float* w3,
    const float* w4, const float* w5, const float* w6, short* out)
{
    __shared__ float t[32][33];
    const int z = blockIdx.z;
    const float* W;
    switch (z) {
        case 0: W = w0; break; case 1: W = w1; break; case 2: W = w2; break;
        case 3: W = w3; break; case 4: W = w4; break; case 5: W = w5; break;
        default: W = w6; break;
    }
    short* O = out + (size_t)z * DD * DD;
    const int tid = threadIdx.x;
    const int k0 = blockIdx.y * 32, n0 = blockIdx.x * 32;
    const int r = tid >> 3, c4 = (tid & 7) * 4;
    float4 v = *(const float4*)&W[(size_t)(k0 + r) * DD + n0 + c4];
    t[r][c4+0] = v.x; t[r][c4+1] = v.y; t[r][c4+2] = v.z; t[r][c4+3] = v.w;
    __syncthreads();
    short4 o;
    o.x = f2bf(t[c4+0][r]); o.y = f2bf(t[c4+1][r]);
    o.z = f2bf(t[c4+2][r]); o.w = f2bf(t[c4+3][r]);
    *(short4*)&O[(size_t)(n0 + r) * DD + k0 + c4] = o;
}

__global__ __launch_bounds__(256) void transposeF_kernel(
    const float* __restrict__ W, short* __restrict__ O)
{
    __shared__ float t[32][33];
    const int tid = threadIdx.x;
    const int k0 = blockIdx.y * 32, n0 = blockIdx.x * 32;
    const int r = tid >> 3, c4 = (tid & 7) * 4;
    float4 v = *(const float4*)&W[(size_t)(k0 + r) * VV + n0 + c4];
    t[r][c4+0] = v.x; t[r][c4+1] = v.y; t[r][c4+2] = v.z; t[r][c4+3] = v.w;
    __syncthreads();
    short4 o;
    o.x = f2bf(t[c4+0][r]); o.y = f2bf(t[c4+1][r]);
    o.z = f2bf(t[c4+2][r]); o.w = f2bf(t[c4+3][r]);
    *(short4*)&O[(size_t)(n0 + r) * DD + k0 + c4] = o;
}

// ---------------- mems (L,B,M,D) f32 -> bf16, one pass ---------------------
__global__ __launch_bounds__(256) void memsbf_kernel(
    const float* __restrict__ mems, short* __restrict__ out)
{
    size_t i = ((size_t)blockIdx.x * 256 + threadIdx.x) * 8;
    const float* mp = mems + i;
    float4 a0 = *(const float4*)mp;
    float4 a1 = *(const float4*)(mp + 4);
    s16x8 o;
    o[0] = f2bf(a0.x); o[1] = f2bf(a0.y); o[2] = f2bf(a0.z); o[3] = f2bf(a0.w);
    o[4] = f2bf(a1.x); o[5] = f2bf(a1.y); o[6] = f2bf(a1.z); o[7] = f2bf(a1.w);
    *(s16x8*)(out + i) = o;
}

// ---------------- MFMA flash attention, QB=64 x KVBLK=128 (R10) -----------
__global__ __launch_bounds__(256, 2) void attn_kernel(
    const short* __restrict__ q, const short* __restrict__ k,
    const short* __restrict__ v, const short* __restrict__ Qr,
    short* __restrict__ ctx, int kstr, int qstr)
{
    __shared__ short k_s[128][72];
    __shared__ short vT_s[64][136];  // [d][64h + (t64 ^ swz)]
    __shared__ short qr_s[192][72];  // ring: phys = (rb + idx) mod 192
    __shared__ float a_t[64][68];    // scores; p_s aliases row base after softmax

    const int tid  = threadIdx.x;
    const int id   = blockIdx.x;
    const int bh   = id & 31;
    const int qi   = ((id >> 5) + bh) & 15;
    const int q0   = qi * 64;
    const int b    = bh >> 4;
    const int h    = bh & 15;
    const int hoff = h * DH;

    const int lane = tid & 63;
    const int wave = tid >> 6;
    const int fr   = lane & 15;
    const int fg   = lane >> 4;
    const int tk2 = tid >> 1, ck2 = (tid & 1) * 32;
    const int jq2 = tid >> 1, dqr = (tid & 1) * 32;
    const int j2  = tid >> 2, dq2 = (tid & 3) * 16;
    const int sr  = tid >> 2;
    const int sc0 = (tid & 3) * 16;

    const short* qrow = q + ((size_t)(b * TT + q0 + 16 * wave + fr)) * kstr + hoff;
    s16x8 aq0 = *(const s16x8*)(qrow + fg * 8);
    s16x8 aq1 = *(const s16x8*)(qrow + 32 + fg * 8);

    float m_r = -1e30f, l_r = 0.0f;

    const int t_end = q0 + 64 + MEM;
    const int u0b   = SS - 1 - q0 - 63;

    s16x8 kf[4], vf[4], rgq[4], rgq2[2];
    auto loadKV = [&](int t0n) {
        const short* kp = k + ((size_t)(b * TT + t0n + tk2)) * kstr + hoff + ck2;
        const short* vp = v + ((size_t)(b * TT + t0n + tk2)) * kstr + hoff + ck2;
        #pragma unroll
        for (int i = 0; i < 4; ++i) {
            kf[i] = *(const s16x8*)(kp + 8 * i);
            vf[i] = *(const s16x8*)(vp + 8 * i);
        }
    };
    auto loadQR = [&](int t0n) {
        int u = t0n + u0b + 63 + jq2;
        u = u > TT - 1 ? TT - 1 : u;
        const short* rp = Qr + (size_t)u * qstr + hoff + dqr;
        #pragma unroll
        for (int i = 0; i < 4; ++i) rgq[i] = *(const s16x8*)(rp + 8 * i);
    };
    {   // init: window(0) idx 0..191
        int u1 = u0b + jq2;
        u1 = u1 > TT - 1 ? TT - 1 : u1;
        const short* rp1 = Qr + (size_t)u1 * qstr + hoff + dqr;
        #pragma unroll
        for (int i = 0; i < 4; ++i) rgq[i] = *(const s16x8*)(rp1 + 8 * i);
        int u2 = u0b + 128 + j2;
        u2 = u2 > TT - 1 ? TT - 1 : u2;
        const short* rp2 = Qr + (size_t)u2 * qstr + hoff + dq2;
        rgq2[0] = *(const s16x8*)rp2;
        rgq2[1] = *(const s16x8*)(rp2 + 8);
    }
    loadKV(0);

    f32x4 opv[4] = {};
    const int nlo = 3 - wave, nhi = 7 - wave;
    int rb = 0;

    auto computeHalf = [&](int hh, int t0) {
        {   // QK -> a_t
            __builtin_amdgcn_s_setprio(1);
            #pragma unroll
            for (int n = 0; n < 4; ++n) {
                s16x8 b0 = *(const s16x8*)&k_s[64*hh + 16*n + fr][fg * 8];
                s16x8 b1 = *(const s16x8*)&k_s[64*hh + 16*n + fr][32 + fg * 8];
                f32x4 ca = {0, 0, 0, 0};
                ca = __builtin_amdgcn_mfma_f32_16x16x32_bf16(aq0, b0, ca, 0, 0, 0);
                ca = __builtin_amdgcn_mfma_f32_16x16x32_bf16(aq1, b1, ca, 0, 0, 0);
                #pragma unroll
                for (int rg = 0; rg < 4; ++rg)
                    a_t[16*wave + 4*fg + rg][16*n + fr] = ca[rg];
            }
            __builtin_amdgcn_s_setprio(0);
        }
        {   // QR band -> scatter-ADD (ring read, intra-wave rows)
            #pragma unroll
            for (int n = 0; n < 8; ++n) {
                if (n < nlo || n > nhi) continue;
                int pr = rb + 64*hh + 16*n + fr;
                if (pr >= 192) pr -= 192;
                s16x8 c0 = *(const s16x8*)&qr_s[pr][fg * 8];
                s16x8 c1 = *(const s16x8*)&qr_s[pr][32 + fg * 8];
                f32x4 cb = {0, 0, 0, 0};
                cb = __builtin_amdgcn_mfma_f32_16x16x32_bf16(aq0, c0, cb, 0, 0, 0);
                cb = __builtin_amdgcn_mfma_f32_16x16x32_bf16(aq1, c1, cb, 0, 0, 0);
                #pragma unroll
                for (int rg = 0; rg < 4; ++rg) {
                    const int r  = 16*wave + 4*fg + rg;
                    const int tl = 16*n + fr - 63 + r;
                    if ((unsigned)tl < 64u) a_t[r][tl] += cb[rg];
                }
            }
        }
        {   // online softmax (intra-wave), P -> bf16 aliased onto a_t rows
            const int sg = q0 + sr;
            const int tb = t0 + 64*hh;
            float e[16];
            float mx = -1e30f;
            #pragma unroll
            for (int j = 0; j < 16; ++j) {
                const int c = sc0 + j;
                float x = a_t[sr][c] * 0.125f;
                x = (tb + c > sg + MEM) ? -1e30f : x;
                e[j] = x;
                mx = fmaxf(mx, x);
            }
            mx = fmaxf(mx, __shfl_xor(mx, 1, 64));
            mx = fmaxf(mx, __shfl_xor(mx, 2, 64));
            const float mn  = fmaxf(m_r, mx);
            const float scl = __expf(m_r - mn);
            float sum = 0.0f;
            s16x8 p0, p1;
            #pragma unroll
            for (int j = 0; j < 16; ++j) {
                float ev = __expf(e[j] - mn);
                sum += ev;
                if (j < 8) p0[j] = f2bf(ev); else p1[j - 8] = f2bf(ev);
            }
            sum += __shfl_xor(sum, 1, 64);
            sum += __shfl_xor(sum, 2, 64);
            l_r = l_r * scl + sum;
            m_r = mn;
            short* prow = (short*)&a_t[sr][0];
            *(s16x8*)&prow[sc0]     = p0;
            *(s16x8*)&prow[sc0 + 8] = p1;
            asm volatile("s_waitcnt lgkmcnt(0)" ::: "memory");
            __builtin_amdgcn_sched_barrier(0);

            f32x4 scv;
            #pragma unroll
            for (int rg = 0; rg < 4; ++rg) scv[rg] = __shfl(scl, 16*fg + 4*rg, 64);
            #pragma unroll
            for (int n = 0; n < 4; ++n)
                #pragma unroll
                for (int rg = 0; rg < 4; ++rg) opv[n][rg] *= scv[rg];
            const short* pv = (const short*)&a_t[16*wave + fr][0];
            s16x8 ap0 = *(const s16x8*)&pv[fg * 8];
            s16x8 ap1 = *(const s16x8*)&pv[32 + fg * 8];
            __builtin_amdgcn_s_setprio(1);
            #pragma unroll
            for (int n = 0; n < 4; ++n) {
                const int d  = 16*n + fr;
                const int xw = (d >> 3) & 3;
                s16x8 bv0 = *(const s16x8*)&vT_s[d][64*hh + (fg ^ xw) * 8];
                s16x8 bv1 = *(const s16x8*)&vT_s[d][64*hh + 32 + (fg ^ xw) * 8];
                opv[n] = __builtin_amdgcn_mfma_f32_16x16x32_bf16(ap0, bv0, opv[n], 0, 0, 0);
                opv[n] = __builtin_amdgcn_mfma_f32_16x16x32_bf16(ap1, bv1, opv[n], 0, 0, 0);
            }
            __builtin_amdgcn_s_setprio(0);
        }
    };

    for (int t0 = 0; t0 < t_end; t0 += 128) {
        asm volatile("" ::: "memory");
        __builtin_amdgcn_s_barrier();
        __builtin_amdgcn_sched_barrier(0);
        {
            #pragma unroll
            for (int i = 0; i < 4; ++i)
                *(s16x8*)&k_s[tk2][ck2 + 8*i] = kf[i];
            #pragma unroll
            for (int i = 0; i < 4; ++i) {
                #pragma unroll
                for (int e = 0; e < 8; ++e) {
                    const int d = ck2 + 8*i + e;
                    const int col = 64*(tk2 >> 6) + ((tk2 & 63) ^ (((d >> 3) & 3) << 3));
                    vT_s[d][col] = vf[i][e];
                }
            }
            if (t0 == 0) {
                #pragma unroll
                for (int i = 0; i < 4; ++i)
                    *(s16x8*)&qr_s[jq2][dqr + 8*i] = rgq[i];
                *(s16x8*)&qr_s[128 + j2][dq2]     = rgq2[0];
                *(s16x8*)&qr_s[128 + j2][dq2 + 8] = rgq2[1];
            } else {
                int p = rb + 63 + jq2;
                if (p >= 192) p -= 192;
                #pragma unroll
                for (int i = 0; i < 4; ++i)
                    *(s16x8*)&qr_s[p][dqr + 8*i] = rgq[i];
            }
        }
        if (t0 + 128 < t_end) { loadKV(t0 + 128); loadQR(t0 + 128); }
        asm volatile("s_waitcnt lgkmcnt(0)" ::: "memory");
        __builtin_amdgcn_s_barrier();
        __builtin_amdgcn_sched_barrier(0);

        computeHalf(0, t0);
        if (t0 + 64 < t_end) computeHalf(1, t0);

        rb += 128; if (rb >= 192) rb -= 192;
    }

    {
        f32x4 lv;
        #pragma unroll
        for (int rg = 0; rg < 4; ++rg) lv[rg] = __shfl(l_r, 16*fg + 4*rg, 64);
        #pragma unroll
        for (int rg = 0; rg < 4; ++rg) {
            const int r = 16*wave + 4*fg + rg;
            const float inv = 1.0f / lv[rg];
            short* op = ctx + ((size_t)(b * SS + q0 + r)) * DD + hoff;
            #pragma unroll
            for (int n = 0; n < 4; ++n)
                op[16*n + fr] = f2bf(opv[n][rg] * inv);
        }
    }
}

// ---------------- add + LayerNorm, dual f32 + bf16 output ----------------
__global__ __launch_bounds__(256) void addln_kernel(
    const float* __restrict__ a, const float* __restrict__ b,
    const float* __restrict__ g, const float* __restrict__ be,
    float* __restrict__ out32, short* __restrict__ outbf)
{
    __shared__ float red[8];
    const int row = blockIdx.x;
    const int tid = threadIdx.x;
    const size_t base = (size_t)row * DD;
    const int c = tid * 4;
    float4 xa = *(const float4*)(a + base + c);
    float4 xb = *(const float4*)(b + base + c);
    float x0 = xa.x + xb.x, x1 = xa.y + xb.y, x2 = xa.z + xb.z, x3 = xa.w + xb.w;
    float s  = x0 + x1 + x2 + x3;
    float sq = x0 * x0 + x1 * x1 + x2 * x2 + x3 * x3;
    #pragma unroll
    for (int o = 32; o > 0; o >>= 1) {
        s  += __shfl_down(s, o, 64);
        sq += __shfl_down(sq, o, 64);
    }
    const int wv = tid >> 6;
    if ((tid & 63) == 0) { red[wv * 2] = s; red[wv * 2 + 1] = sq; }
    __syncthreads();
    float ts = red[0] + red[2] + red[4] + red[6];
    float tq = red[1] + red[3] + red[5] + red[7];
    float mu  = ts * (1.0f / DD);
    float var = tq * (1.0f / DD) - mu * mu;
    float rs  = rsqrtf(var + 1e-5f);
    float4 gv = *(const float4*)(g + c);
    float4 bv = *(const float4*)(be + c);
    float4 o4;
    o4.x = (x0 - mu) * rs * gv.x + bv.x;
    o4.y = (x1 - mu) * rs * gv.y + bv.y;
    o4.z = (x2 - mu) * rs * gv.z + bv.z;
    o4.w = (x3 - mu) * rs * gv.w + bv.w;
    *(float4*)(out32 + base + c) = o4;
    short4 ob;
    ob.x = f2bf(o4.x); ob.y = f2bf(o4.y); ob.z = f2bf(o4.z); ob.w = f2bf(o4.w);
    *(short4*)(outbf + base + c) = ob;
}

// ---------------- embedding gather * sqrt(D), dual output ----------------
__global__ __launch_bounds__(256) void embed_kernel(
    const int* __restrict__ inp, const float* __restrict__ emb,
    float* __restrict__ x32, short* __restrict__ xbf)
{
    const int row = blockIdx.x;
    const int c = threadIdx.x * 4;
    const int idx = inp[row];
    float4 vv = *(const float4*)(emb + (size_t)idx * DD + c);
    vv.x *= 32.0f; vv.y *= 32.0f; vv.z *= 32.0f; vv.w *= 32.0f;
    *(float4*)(x32 + (size_t)row * DD + c) = vv;
    short4 ob;
    ob.x = f2bf(vv.x); ob.y = f2bf(vv.y); ob.z = f2bf(vv.z); ob.w = f2bf(vv.w);
    *(short4*)(xbf + (size_t)row * DD + c) = ob;
}

// ---------------- reversed sinusoidal position encoding (bf16) ------------
__global__ __launch_bounds__(256) void relenc_kernel(short* __restrict__ re)
{
    const int u = blockIdx.x;
    const int p = TT - 1 - u;
    const int i0 = threadIdx.x * 4;
    short4 o;
    #pragma unroll
    for (int j = 0; j < 4; ++j) {
        int i = i0 + j;
        float ex   = (float)(2 * (i >> 1)) * (1.0f / DD);
        float invf = __expf(-ex * 9.210340371976184f);
        float ang  = (float)p * invf;
        float val  = (i & 1) ? cosf(ang) : sinf(ang);
        ((short*)&o)[j] = f2bf(val);
    }
    *(short4*)&re[(size_t)u * DD + i0] = o;
}

extern "C" void kernel_launch(void* const* d_in, const int* in_sizes, int n_in,
                              void* d_out, int out_size, void* d_ws, size_t ws_size,
                              hipStream_t stream)
{
    const int*   inp  = (const int*)d_in[0];
    const float* mems = (const float*)d_in[1];
    const float* emb  = (const float*)d_in[2];
    const float* Wq   = (const float*)d_in[3];
    const float* bq   = (const float*)d_in[4];
    const float* Wke  = (const float*)d_in[5];
    const float* bke  = (const float*)d_in[6];
    const float* Wkr  = (const float*)d_in[7];
    const float* bkr  = (const float*)d_in[8];
    const float* Wv   = (const float*)d_in[9];
    const float* bv   = (const float*)d_in[10];
    const float* Wo   = (const float*)d_in[11];
    const float* bo   = (const float*)d_in[12];
    const float* ln1g = (const float*)d_in[13];
    const float* ln1b = (const float*)d_in[14];
    const float* W1   = (const float*)d_in[15];
    const float* b1   = (const float*)d_in[16];
    const float* W2   = (const float*)d_in[17];
    const float* b2   = (const float*)d_in[18];
    const float* ln2g = (const float*)d_in[19];
    const float* ln2b = (const float*)d_in[20];
    const float* Wh   = (const float*)d_in[21];
    const float* bh   = (const float*)d_in[22];
    const float* Wf   = (const float*)d_in[23];
    const float* bfb  = (const float*)d_in[24];

    hipFuncSetAttribute((const void*)gemm8p,
                        hipFuncAttributeMaxDynamicSharedMemorySize, 131072);
    hipFuncSetAttribute((const void*)gemm8n,
                        hipFuncAttributeMaxDynamicSharedMemorySize, 147456);

    char* wsb = (char*)d_ws;
    size_t off = 0;
    auto alloc = [&](size_t bytes) { char* p = wsb + off; off += (bytes + 255) & ~(size_t)255; return p; };
    float* h132  = (float*)alloc((size_t)BB*SS*DD*4);
    float* ao32  = (float*)alloc((size_t)BB*SS*DD*4);
    float* ff232 = (float*)alloc((size_t)BB*SS*DD*4);
    short* qkvb  = (short*)alloc((size_t)BB*TT*3*DD*2);   // [B*T][3072]: q|k|v
    short* ctxb  = (short*)alloc((size_t)BB*SS*DD*2);
    short* ff1   = (short*)alloc((size_t)BB*SS*DD*2);
    // end transient (~68 MB); aliased by wkr4 (pre-loop) and wft (post-loop)
    float* x32   = (float*)alloc((size_t)BB*SS*DD*4);
    short* x_bf  = (short*)alloc((size_t)BB*SS*DD*2);
    short* whout = (short*)alloc((size_t)BB*SS*DD*2);
    short* rel   = (short*)alloc((size_t)TT*DD*2);
    short* qr4   = (short*)alloc((size_t)TT*4*DD*2);      // [2048][4096] bf16
    short* wt6   = (short*)alloc((size_t)6*DD*DD*2);
    short* msbf  = (short*)alloc((size_t)LL*BB*MEM*DD*2); // mems bf16, all layers
    short* wkr4  = (short*)h132;
    short* wft   = (short*)h132;

    relenc_kernel<<<TT, 256, 0, stream>>>(rel);
    embed_kernel<<<BB * SS, 256, 0, stream>>>(inp, emb, x32, x_bf);
    memsbf_kernel<<<(LL * BB * MEM * DD / 8) / 256, 256, 0, stream>>>(mems, msbf);

    const size_t WOFF = (size_t)DD * DD;

    // hoisted: Qr all layers = rel @ [Wkr0^T|..|Wkr3^T]; bias = bkr (L,D) flat
    transpose7_kernel<<<dim3(32, 32, 4), 256, 0, stream>>>(
        Wkr + 0*WOFF, Wkr + 1*WOFF, Wkr + 2*WOFF, Wkr + 3*WOFF, Wq, Wq, Wq, wkr4);
    gemm8n<<<dim3((TT/256) * (4*DD/128)), 512, 147456, stream>>>(
        rel, rel, wkr4, bkr, bkr, bkr, 4*DD, 4*DD, qr4, 4*DD, DD, TT/256, 0);

    const int gSm = (DD / 64) * ((BB * SS) / 64);   // 512 blocks, 64x64 tiles

    for (int l = 0; l < LL; ++l) {
        const size_t wo  = (size_t)l * DD * DD;
        const size_t bo_ = (size_t)l * DD;
        transpose7_kernel<<<dim3(32, 32, 6), 256, 0, stream>>>(
            Wq + wo, Wke + wo, Wv + wo, Wo + wo, W1 + wo, W2 + wo, Wq, wt6);
        // fused qkv GEMM: trimmed 320-block grid; A = {memsbf layer l | x_bf}
        gemm8n<<<dim3(320), 512, 147456, stream>>>(
            msbf + (size_t)l * BB * MEM * DD, x_bf, wt6,
            bq + bo_, bke + bo_, bv + bo_, DD, 2*DD, qkvb, 3*DD, DD, 0, 1);
        attn_kernel<<<dim3((SS / 64) * BB * NH), 256, 0, stream>>>(
            qkvb + (size_t)MEM * 3 * DD, qkvb + DD, qkvb + 2 * DD,
            qr4 + (size_t)l * DD, ctxb, 3 * DD, 4 * DD);
        gemm_k128<2,2><<<dim3(gSm), 256, 0, stream>>>(
            ctxb, wt6 + 3*WOFF, bo + bo_, bo + bo_, DD, ao32, DD, DD, (BB*SS)/64, 0, 0);
        addln_kernel<<<BB * SS, 256, 0, stream>>>(x32, ao32, ln1g + bo_, ln1b + bo_, h132, x_bf);
        gemm_k128<2,2><<<dim3(gSm), 256, 0, stream>>>(
            x_bf, wt6 + 4*WOFF, b1 + bo_, b1 + bo_, DD, ff1, DD, DD, (BB*SS)/64, 1, 1);
        gemm_k128<2,2><<<dim3(gSm), 256, 0, stream>>>(
            ff1, wt6 + 5*WOFF, b2 + bo_, b2 + bo_, DD, ff232, DD, DD, (BB*SS)/64, 0, 0);
        addln_kernel<<<BB * SS, 256, 0, stream>>>(h132, ff232, ln2g + bo_, ln2b + bo_, x32, x_bf);
    }

    transpose7_kernel<<<dim3(32, 32, 1), 256, 0, stream>>>(
        Wh, Wh, Wh, Wh, Wh, Wh, Wh, wt6);
    transposeF_kernel<<<dim3(VV / 32, DD / 32), 256, 0, stream>>>(Wf, wft);
    gemm_k128<2,2><<<dim3(gSm), 256, 0, stream>>>(
        x_bf, wt6, bh, bh, DD, whout, DD, DD, (BB*SS)/64, 1, 1);
    gemm8p<<<dim3((VV / 256) * ((BB * SS) / 256)), 512, 131072, stream>>>(
        whout, wft, bfb, (float*)d_out, VV);
}